// Round 2
// 4668.227 us; speedup vs baseline: 1.0379x; 1.0379x over previous
//
#include <hip/hip_runtime.h>

// RNN language model:  V=50257, H=1024, O=50257, B=32, T=512
//  2. recurrence: 32 cooperating blocks (one per 32-col slice of H), SH slice
//     LDS-resident (pre-swizzled vs bank conflicts), st in registers.
//     a=exp(st*es) exchanged per step via DATA-AS-FLAG over ONE-SHOT buffers:
//     abuf[t][32][1024] written exactly once per launch (no reuse -> no
//     zeroing protocol). a>0 always (bf16 of exp never rounds to 0), so
//     consumers poll the payload itself (fused detect+load, ONE LLC round
//     trip). Bounded spin (128) + fallback to proven per-wave-flag protocol
//     guarantees forward progress. 2 barriers/step (den_p parity-dbuf; the
//     poll itself orders Alds/pacc across iterations via own-block publish).
//  3. loss GEMM [16384,1024]@[1024,50432] bf16 MFMA, 256x256 tile, BK=32,
//     4-deep LDS ring with counted vmcnt(4) (never 0 in main loop), 2 phases
//     per K-tile, 16 MFMA/phase, setprio around MFMA, XCD-bijective swizzle.
//     Fused exp/row-sum (Z) + token-logit extraction (lt).
#define VV 50257
#define HH 1024
#define OO 50257
#define BB 32
#define TT 512
#define NPAD2 50432      // 197*256 (gemm N padding)
#define MROWS 16384      // TT*BB
#define NBLK 32          // recurrence blocks
#define KTILES 32        // 1024/32

using bf16x8 = __attribute__((ext_vector_type(8))) short;
using f32x4  = __attribute__((ext_vector_type(4))) float;

__device__ __forceinline__ unsigned short f2bf(float x) {
    unsigned u = __float_as_uint(x);
    unsigned r = (u + 0x7FFFu + ((u >> 16) & 1u)) >> 16;   // RNE
    return (unsigned short)r;
}
__device__ __forceinline__ float bf2f(unsigned short h) {
    return __uint_as_float(((unsigned)h) << 16);
}
// exact "some halfword of x is zero" test (nonzero iff a 16-bit half is 0)
__device__ __forceinline__ unsigned hz16(unsigned x) {
    return (x - 0x00010001u) & ~x & 0x80008000u;
}

// device-coherent 16B load / 2B store (bypass stale L1/L2 across XCDs)
__device__ __forceinline__ uint4 load_coh16(const void* p) {
    uint4 v;
    asm volatile("global_load_dwordx4 %0, %1, off sc0 sc1" : "=v"(v) : "v"(p));
    return v;   // caller must s_waitcnt before use
}
__device__ __forceinline__ void store_coh2(void* p, unsigned short s) {
    unsigned v = s;
    asm volatile("global_store_short %0, %1, off sc0 sc1" :: "v"(p), "v"(v) : "memory");
}
// async global->LDS 16B (per-lane global addr; LDS dest = wave-uniform base + lane*16)
__device__ __forceinline__ void gload16(const void* g, void* l) {
    __builtin_amdgcn_global_load_lds((const __attribute__((address_space(1))) unsigned int*)g,
                                     (__attribute__((address_space(3))) unsigned int*)l, 16, 0, 0);
}

// ---------------- phase 1 kernels ----------------
__global__ void prep_reduce(const float* __restrict__ ih, const float* __restrict__ hh,
                            const float* __restrict__ bias,
                            float* __restrict__ rs, float* __restrict__ rn, float* __restrict__ bsum) {
    int w = blockIdx.x * 4 + (threadIdx.x >> 6);
    int lane = threadIdx.x & 63;
    if (w < 1024) {
        const float* row = ih + (size_t)w * HH;
        float s = 0.f;
        for (int k = lane; k < HH; k += 64) s += row[k];
        for (int m = 1; m < 64; m <<= 1) s += __shfl_xor(s, m, 64);
        if (lane == 0) rs[w] = s;
    } else if (w < 2048) {
        int r = w - 1024;
        const float* row = hh + (size_t)r * HH;
        float s = 0.f;
        for (int k = lane; k < HH; k += 64) { float x = row[k]; s += x * x; }
        for (int m = 1; m < 64; m <<= 1) s += __shfl_xor(s, m, 64);
        if (lane == 0) rn[r] = sqrtf(s);
    } else if (w == 2048) {
        float s = 0.f;
        for (int k = lane; k < HH; k += 64) s += bias[k];
        for (int m = 1; m < 64; m <<= 1) s += __shfl_xor(s, m, 64);
        if (lane == 0) bsum[0] = s;
    }
}

// SHb bf16 blocked col-slices, PRE-SWIZZLED: data for (slice, kb, col) stored at
// (slice, kb, col ^ (kb&3)) so the LDS B-operand read is bank-conflict-free.
__global__ void shconv(const float* __restrict__ hh, const float* __restrict__ rn,
                       unsigned short* __restrict__ SHb) {
    int gid = blockIdx.x * 256 + threadIdx.x;      // 32*128*32 = 131072
    int slice = gid >> 12, kb = (gid >> 5) & 127, col = gid & 31;
    int j = slice * 32 + col;
    float inv = 1.0f / (rn[j] * 1024.0f);
    unsigned short v[8];
#pragma unroll
    for (int e = 0; e < 8; e++)
        v[e] = f2bf(hh[(size_t)(kb * 8 + e) * HH + j] * inv);
    uint4 pk;
    pk.x = (unsigned)v[0] | ((unsigned)v[1] << 16);
    pk.y = (unsigned)v[2] | ((unsigned)v[3] << 16);
    pk.z = (unsigned)v[4] | ((unsigned)v[5] << 16);
    pk.w = (unsigned)v[6] | ((unsigned)v[7] << 16);
    int gid_sw = (slice << 12) + (kb << 5) + (col ^ (kb & 3));
    *(uint4*)(SHb + (size_t)gid_sw * 8) = pk;
}

// esum[v] = sum_i tanh(emb[v][i]) * rs[i] + bsum
__global__ void esum_kernel(const float* __restrict__ emb, const float* __restrict__ rs,
                            const float* __restrict__ bsum, float* __restrict__ esum) {
    __shared__ float rs_l[HH];
    for (int i = threadIdx.x; i < HH; i += 256) rs_l[i] = rs[i];
    __syncthreads();
    int v = blockIdx.x * 4 + (threadIdx.x >> 6);
    if (v >= VV) return;
    int lane = threadIdx.x & 63;
    const float* row = emb + (size_t)v * HH;
    float s = 0.f;
    for (int k = lane; k < HH; k += 64) s += tanhf(row[k]) * rs_l[k];
    for (int m = 1; m < 64; m <<= 1) s += __shfl_xor(s, m, 64);
    if (lane == 0) esum[v] = s + bsum[0];
}

// esd[t*32+b] = esum[tokens[b*512+t]]
__global__ void esd_k(const int* __restrict__ tokens, const float* __restrict__ esum,
                      float* __restrict__ esd) {
    int idx = blockIdx.x * 256 + threadIdx.x;
    int t = idx >> 5, b = idx & 31;
    esd[idx] = esum[tokens[b * TT + t]];
}

// out_w fp32 [H][O] -> bf16 blocked Wb[(k/8)][n][8], n padded/zeroed to NPAD2
__global__ void wconv(const float* __restrict__ W, unsigned short* __restrict__ Wb) {
    int n = blockIdx.x * 256 + threadIdx.x;
    int kb = blockIdx.y;
    unsigned short v[8];
#pragma unroll
    for (int e = 0; e < 8; e++) {
        float x = (n < OO) ? W[(size_t)(kb * 8 + e) * OO + n] : 0.0f;
        v[e] = f2bf(x);
    }
    uint4 pk;
    pk.x = (unsigned)v[0] | ((unsigned)v[1] << 16);
    pk.y = (unsigned)v[2] | ((unsigned)v[3] << 16);
    pk.z = (unsigned)v[4] | ((unsigned)v[5] << 16);
    pk.w = (unsigned)v[6] | ((unsigned)v[7] << 16);
    *(uint4*)(Wb + ((size_t)kb * NPAD2 + n) * 8) = pk;
}

// tokd[t*32+b] = tokens[b*512+t]
__global__ void tokd_k(const int* __restrict__ tokens, int* __restrict__ tokd) {
    int r = blockIdx.x * 256 + threadIdx.x;
    int t = r >> 5, b = r & 31;
    tokd[r] = tokens[b * TT + t];
}

// ---------------- phase 2: recurrence (32 cooperating blocks) ----------------
// a-exchange (data-as-flag, one-shot buffers):
//   abuf[t][32][1024] bf16, zero-init once per launch. publish a(t) into
//   abuf[t] as 2B coherent stores. consume a(t): spin on coherent 16B loads
//   of abuf[t] until every halfword of my 8 chunks is nonzero (exp output is
//   always a nonzero bf16; buffers are write-once so stale data can't exist).
//   Bounded spin (128) then fallback: per-wave flags (flags[blk*4+w], each
//   kh==0 wave drains its own publishes then stores t+2), wait all 128 >=
//   t+1, reload once. Fallback is the proven round-0 protocol => no deadlock.
// Intra-block: den_p parity-double-buffered; Alds/pacc cross-iteration
// hazards ordered by the 2 barriers + the poll (which requires own-block
// publish, which requires own kh==0 waves past the previous epilogue).
__global__ void __launch_bounds__(512) recurrence(
    const float* __restrict__ state_in, const unsigned short* __restrict__ SHb,
    const float* __restrict__ esd, unsigned short* __restrict__ S,
    unsigned short* __restrict__ abuf /*[TT][32][1024] zero-init*/,
    unsigned* __restrict__ flags /*[128][16] zero-init*/,
    float* __restrict__ out_state) {
    __shared__ unsigned short Wl[32768];   // 64 KB: [kb=128][col=32][8] (pre-swizzled)
    __shared__ unsigned short Alds[32768]; // 64 KB: a[32][1024], XOR-swizzled
    __shared__ f32x4 pacc[4][64];          // 4 KB  K-half partials
    __shared__ float den_p[2][8][8];       // wave-partial row sums, t-parity dbuf
    const int blk = blockIdx.x;
    const int tid = threadIdx.x;
    const int lane = tid & 63, w = tid >> 6;
    const int wr = (w >> 1) & 1, nt = w & 1, kh = w >> 2;
    const int q = lane >> 4, l16 = lane & 15;

    float st[4];
    const int b0 = wr * 16 + q * 4;
    const int jg = blk * 32 + nt * 16 + l16;
    // publish a(0) ASAP into abuf[0]; peers poll the data itself
    if (kh == 0) {
#pragma unroll
        for (int r = 0; r < 4; r++) st[r] = state_in[(b0 + r) * HH + jg];
#pragma unroll
        for (int r = 0; r < 4; r++)
            store_coh2(abuf + (size_t)(b0 + r) * HH + jg, f2bf(__expf(st[r] * esd[b0 + r])));
        asm volatile("s_waitcnt vmcnt(0)" ::: "memory");
        if (lane == 0) {
            unsigned one = 1;
            asm volatile("global_store_dword %0, %1, off sc0 sc1"
                         :: "v"(flags + (blk * 4 + w) * 16), "v"(one) : "memory");
        }
    }
    // W slice -> LDS (once); overlaps peers' a(0) publishes
    {
        const uint4* src = (const uint4*)(SHb + (size_t)blk * 32768);
        uint4* dst = (uint4*)Wl;
#pragma unroll
        for (int i = 0; i < 8; i++) dst[tid + i * 512] = src[tid + i * 512];
    }

    for (int t = 0; t < TT; t++) {
        // store S[t] + prefetch next es BEFORE polling (overlaps with peers finishing)
        f32x4 es4;
        if (kh == 0) {
            int tn = (t < TT - 1) ? t + 1 : TT - 1;
            es4 = *(const f32x4*)&esd[tn * BB + b0];
#pragma unroll
            for (int r = 0; r < 4; r++)
                S[(size_t)(t * BB + b0 + r) * HH + jg] = f2bf(st[r]);
        }
        // data-as-flag poll: spin until all 64 halfwords of my 8 chunks of
        // abuf[t] are nonzero. Proven primitive sequence: separate coherent
        // loads, one vmcnt(0), sched_barrier(0) so the check can't be hoisted.
        uint4 v[8];
        {
            const uint4* p0 = (const uint4*)abuf + (size_t)t * 4096 + tid;
            bool ok;
            int spins = 0;
            do {
#pragma unroll
                for (int i = 0; i < 8; i++) v[i] = load_coh16(p0 + i * 512);
                asm volatile("s_waitcnt vmcnt(0)" ::: "memory");
                __builtin_amdgcn_sched_barrier(0);
                unsigned bad = 0;
#pragma unroll
                for (int i = 0; i < 8; i++)
                    bad |= hz16(v[i].x) | hz16(v[i].y) | hz16(v[i].z) | hz16(v[i].w);
                ok = __all(bad == 0);
            } while (!ok && ++spins < 128);
            if (!ok) {
                // fallback: proven flag protocol (per-wave flags, monotone)
                const unsigned* f0 = flags + (2 * lane) * 16;
                const unsigned* f1 = flags + (2 * lane + 1) * 16;
                unsigned fa, fb;
                do {
                    asm volatile("global_load_dword %0, %2, off sc0 sc1\n\t"
                                 "global_load_dword %1, %3, off sc0 sc1\n\t"
                                 "s_waitcnt vmcnt(0)"
                                 : "=&v"(fa), "=&v"(fb) : "v"(f0), "v"(f1) : "memory");
                } while (!__all((int)(fa >= (unsigned)(t + 1) && fb >= (unsigned)(t + 1))));
#pragma unroll
                for (int i = 0; i < 8; i++) v[i] = load_coh16(p0 + i * 512);
                asm volatile("s_waitcnt vmcnt(0)" ::: "memory");
                __builtin_amdgcn_sched_barrier(0);
            }
        }
        // LDS write (swizzled) + den partials from registers
        float p[8];
#pragma unroll
        for (int i = 0; i < 8; i++) {
            int c = tid + i * 512;
            int byte = c * 16;
            int row = byte >> 11;
            *(uint4*)((char*)Alds + (byte ^ ((row & 7) << 4))) = v[i];
            float s = 0.f;
            const unsigned short* hp = (const unsigned short*)&v[i];
#pragma unroll
            for (int e = 0; e < 8; e++) s += bf2f(hp[e]);
            p[i] = s;
        }
#pragma unroll
        for (int i = 0; i < 8; i++) {
            float s = p[i];
            for (int m = 1; m < 64; m <<= 1) s += __shfl_xor(s, m, 64);
            p[i] = s;
        }
        if (lane == 0) {
#pragma unroll
            for (int i = 0; i < 8; i++) den_p[t & 1][w][i] = p[i];
        }
        __syncthreads();                               // Alds + den_p ready
        // MFMA: acc = a[tile-rows][K-half] . W[K-half][tile-cols]
        f32x4 acc = {0.f, 0.f, 0.f, 0.f};
#pragma unroll 4
        for (int kt = kh * 16; kt < kh * 16 + 16; kt++) {
            int arow = wr * 16 + l16;
            int abyte = (arow << 11) + kt * 64 + q * 16;
            abyte ^= (arow & 7) << 4;
            bf16x8 af = *(const bf16x8*)((const char*)Alds + abyte);
            int bbyte = ((kt * 4 + q) << 9) + (((nt * 16 + l16) ^ q) << 4);  // pre-swizzled W
            bf16x8 bfv = *(const bf16x8*)((const char*)Wl + bbyte);
            acc = __builtin_amdgcn_mfma_f32_16x16x32_bf16(af, bfv, acc, 0, 0, 0);
        }
        const int tile = wr * 2 + nt;
        if (kh == 1) pacc[tile][lane] = acc;
        __syncthreads();                               // pacc ready
        if (kh == 0) {
            f32x4 other = pacc[tile][lane];
            const bool last = (t == TT - 1);
#pragma unroll
            for (int r = 0; r < 4; r++) {
                float den = den_p[t & 1][2 * r][wr * 4 + q] + den_p[t & 1][2 * r + 1][wr * 4 + q];
                float u = (acc[r] + other[r]) / den;
                float stn = tanhf(st[r] + u);
                st[r] = stn;
                if (!last)
                    store_coh2(abuf + (size_t)(t + 1) * (BB * HH) +
                               (size_t)(b0 + r) * HH + jg, f2bf(__expf(stn * es4[r])));
            }
            if (!last) {
                // drain own publishes, then raise this wave's flag (fallback path)
                asm volatile("s_waitcnt vmcnt(0)" ::: "memory");
                if (lane == 0) {
                    unsigned val = (unsigned)(t + 2);
                    asm volatile("global_store_dword %0, %1, off sc0 sc1"
                                 :: "v"(flags + (blk * 4 + w) * 16), "v"(val) : "memory");
                }
            }
        }
        // no end-of-step barrier: cross-iteration LDS hazards are covered by
        // the two barriers above + den_p parity + poll-as-barrier (see header)
    }
    if (kh == 0) {
#pragma unroll
        for (int r = 0; r < 4; r++) out_state[(b0 + r) * HH + jg] = st[r];
    }
}

// ---------------- phase 3: 256x256 BK=32 pipelined GEMM + fused CE ----------------
// 8 waves: wm = w>>2 (2), wn = w&3 (4); wave C-block 128 rows x 64 cols.
// LDS ring: 4 K-tile buffers (A 16KB [256 rows][4 slots][16B], slot^=row&3;
//                             B 16KB [4 kb][256 n][16B]).
// Prefetch distance 2 K-tiles -> writes never touch a buffer readers still need.
__global__ void __launch_bounds__(512) gemm_ce(
    const unsigned short* __restrict__ S, const unsigned short* __restrict__ Wb,
    const float* __restrict__ outBias, const int* __restrict__ tokd,
    float* __restrict__ Z, float* __restrict__ lt) {
    __shared__ unsigned short Ab[4][8192];
    __shared__ unsigned short Bb[4][8192];
    const int tid = threadIdx.x;
    const int lane = tid & 63, w = tid >> 6;
    const int wm = w >> 2, wn = w & 3;
    // XCD-bijective swizzle (12608 = 8*1576) + 8-m-tile chunks for L2 reuse
    const int lin = blockIdx.x;
    const int id = (lin & 7) * 1576 + (lin >> 3);
    const int grp = id / (197 * 8);
    const int rem = id % (197 * 8);
    const int bx = rem >> 3;
    const int by = (grp << 3) + (rem & 7);
    const int bx256 = bx * 256, by256 = by * 256;

    // staging decode
    const int arow = tid >> 2;                                  // 0..127
    const int rswA = (((tid & 3) ^ (arow & 3)) << 3);           // pre-swizzled k-offset (elems)
    const unsigned short* AsrcBase = S + (size_t)(by256 + arow) * 1024 + rswA;
    const unsigned short* BsrcBase = Wb + ((size_t)(tid >> 8) * NPAD2 + bx256 + (tid & 255)) * 8;

#define ISSUE_A(kt_) { unsigned short* d = Ab[(kt_) & 3];                         \
    const unsigned short* s0 = AsrcBase + (kt_) * 32;                             \
    gload16(s0, (char*)d + tid * 16);                                             \
    gload16(s0 + 128 * 1024, (char*)d + 8192 + tid * 16); }
#define ISSUE_B(kt_) { unsigned short* d = Bb[(kt_) & 3];                         \
    const unsigned short* s0 = BsrcBase + (size_t)(kt_) * 4 * NPAD2 * 8;          \
    gload16(s0, (char*)d + tid * 16);                                             \
    gload16(s0 + (size_t)2 * NPAD2 * 8, (char*)d + 8192 + tid * 16); }

    f32x4 acc[8][4];
#pragma unroll
    for (int mi = 0; mi < 8; mi++)
#pragma unroll
        for (int ni = 0; ni < 4; ni++) acc[mi][ni] = {0.f, 0.f, 0.f, 0.f};

    // prologue: K0,K1 in flight; wait K0
    ISSUE_A(0); ISSUE_B(0); ISSUE_A(1); ISSUE_B(1);
    asm volatile("s_waitcnt vmcnt(4)" ::: "memory");
    __builtin_amdgcn_s_barrier();

    const int l15 = lane & 15;
    const int slotA = (((lane >> 4) ^ (lane & 3)) << 4);        // byte offset of swizzled slot
    const int browA = wm * 128 + l15;                           // + mi*16
    const int bcolB = ((lane >> 4) << 12) + ((wn * 64 + l15) << 4);  // + ni*256B

    for (int kt = 0; kt < KTILES; kt++) {
        const char* Abase = (const char*)Ab[kt & 3];
        const char* Bbase = (const char*)Bb[kt & 3];
        bf16x8 af[4], bf[4];
        // ---- phase 1: m0-3 x n0-3 ----
#pragma unroll
        for (int mi = 0; mi < 4; mi++)
            af[mi] = *(const bf16x8*)(Abase + ((browA + mi * 16) << 6) + slotA);
#pragma unroll
        for (int ni = 0; ni < 4; ni++)
            bf[ni] = *(const bf16x8*)(Bbase + bcolB + ni * 256);
        if (kt < KTILES - 2) ISSUE_A(kt + 2);
        __builtin_amdgcn_s_barrier();
        asm volatile("s_waitcnt lgkmcnt(0)" ::: "memory");
        __builtin_amdgcn_sched_barrier(0);
        __builtin_amdgcn_s_setprio(1);
#pragma unroll
        for (int mi = 0; mi < 4; mi++)
#pragma unroll
            for (int ni = 0; ni < 4; ni++)
                acc[mi][ni] = __builtin_amdgcn_mfma_f32_16x16x32_bf16(af[mi], bf[ni], acc[mi][ni], 0, 0, 0);
        __builtin_amdgcn_s_setprio(0);
        __builtin_amdgcn_s_barrier();
        // ---- phase 2: m4-7 x n0-3 (B reused from regs) ----
#pragma unroll
        for (int mi = 0; mi < 4; mi++)
            af[mi] = *(const bf16x8*)(Abase + ((browA + (mi + 4) * 16) << 6) + slotA);
        if (kt < KTILES - 2) ISSUE_B(kt + 2);
        __builtin_amdgcn_s_barrier();
        asm volatile("s_waitcnt lgkmcnt(0)" ::: "memory");
        __builtin_amdgcn_sched_barrier(0);
        __builtin_amdgcn_s_setprio(1);
#pragma unroll
        for (int mi = 0; mi < 4; mi++)
#pragma unroll
            for (int ni = 0; ni < 4; ni++)
                acc[mi + 4][ni] = __builtin_amdgcn_mfma_f32_16x16x32_bf16(af[mi], bf[ni], acc[mi + 4][ni], 0, 0, 0);
        __builtin_amdgcn_s_setprio(0);
        // K-tile boundary: ensure next tile resident; never drain to 0 until epilogue
        if (kt < KTILES - 3) {
            asm volatile("s_waitcnt vmcnt(4)" ::: "memory");
        } else if (kt == KTILES - 3) {
            asm volatile("s_waitcnt vmcnt(0)" ::: "memory");
        }
        __builtin_amdgcn_s_barrier();
    }
#undef ISSUE_A
#undef ISSUE_B

    // epilogue: logit = acc + outBias; e = exp; row sums -> atomicAdd Z; token logit -> lt
    const int colb = bx256 + wn * 64;
    const int rbase = by256 + wm * 128 + ((lane >> 4) << 2);
    float obv[4]; bool okv[4]; int jjv[4];
#pragma unroll
    for (int ni = 0; ni < 4; ni++) {
        jjv[ni] = colb + ni * 16 + l15;
        okv[ni] = jjv[ni] < OO;
        obv[ni] = okv[ni] ? outBias[jjv[ni]] : 0.f;
    }
    float rsum[8][4];
#pragma unroll
    for (int mi = 0; mi < 8; mi++)
#pragma unroll
        for (int r = 0; r < 4; r++) {
            int row = rbase + mi * 16 + r;
            int tk = tokd[row];
            float rssum = 0.f;
#pragma unroll
            for (int ni = 0; ni < 4; ni++) {
                float lg = acc[mi][ni][r] + obv[ni];
                rssum += okv[ni] ? __expf(lg) : 0.f;
                if (okv[ni] && jjv[ni] == tk) lt[row] = lg;
            }
            rsum[mi][r] = rssum;
        }
#pragma unroll
    for (int mi = 0; mi < 8; mi++)
#pragma unroll
        for (int r = 0; r < 4; r++) {
            float s = rsum[mi][r];
            s += __shfl_xor(s, 1, 64); s += __shfl_xor(s, 2, 64);
            s += __shfl_xor(s, 4, 64); s += __shfl_xor(s, 8, 64);
            rsum[mi][r] = s;
        }
    if (l15 == 0) {
#pragma unroll
        for (int mi = 0; mi < 8; mi++)
#pragma unroll
            for (int r = 0; r < 4; r++)
                atomicAdd(&Z[rbase + mi * 16 + r], rsum[mi][r]);
    }
}

// ---------------- phase 4: final reduce ----------------
__global__ void __launch_bounds__(1024) loss_reduce(const float* __restrict__ Z,
                                                    const float* __restrict__ lt,
                                                    float* __restrict__ out_loss) {
    __shared__ float red[16];
    float s = 0.f;
    for (int r = threadIdx.x; r < MROWS; r += 1024) s += logf(Z[r]) - lt[r];
    for (int m = 1; m < 64; m <<= 1) s += __shfl_xor(s, m, 64);
    if ((threadIdx.x & 63) == 0) red[threadIdx.x >> 6] = s;
    __syncthreads();
    if (threadIdx.x == 0) {
        float tot = 0.f;
        for (int q = 0; q < 16; q++) tot += red[q];
        out_loss[0] = tot / 32.0f;
    }
}

extern "C" void kernel_launch(void* const* d_in, const int* in_sizes, int n_in,
                              void* d_out, int out_size, void* d_ws, size_t ws_size,
                              hipStream_t stream) {
    const float* state  = (const float*)d_in[0];
    const int*   tokens = (const int*)d_in[1];
    const float* emb    = (const float*)d_in[2];
    const float* ih     = (const float*)d_in[3];
    const float* hh     = (const float*)d_in[4];
    const float* bias   = (const float*)d_in[5];
    const float* outw   = (const float*)d_in[6];
    const float* outb   = (const float*)d_in[7];

    char* ws = (char*)d_ws;
    size_t off = 0;
    auto alloc = [&](size_t bytes) { void* p = ws + off; off += (bytes + 255) & ~(size_t)255; return p; };
    unsigned short* Wb  = (unsigned short*)alloc((size_t)128 * NPAD2 * 8 * 2); // 103.3 MB
    unsigned short* S   = (unsigned short*)alloc((size_t)MROWS * HH * 2);      // 33.5 MB
    unsigned short* abuf= (unsigned short*)alloc((size_t)TT * BB * HH * 2);    // 33.5 MB one-shot
    unsigned short* SHb = (unsigned short*)alloc((size_t)131072 * 8 * 2);      // 2 MB
    float* esum = (float*)alloc((size_t)VV * 4);
    float* esd  = (float*)alloc((size_t)MROWS * 4);
    float* rs   = (float*)alloc(4096);
    float* rn   = (float*)alloc(4096);
    float* bsum = (float*)alloc(256);
    float* Z    = (float*)alloc((size_t)MROWS * 4);
    float* lt   = (float*)alloc((size_t)MROWS * 4);
    int*   tokd = (int*)alloc((size_t)MROWS * 4);
    unsigned* flags = (unsigned*)alloc(128 * 16 * 4);   // per-wave flags, 64B-spaced
    float* out_state = (float*)d_out;
    float* out_loss  = out_state + 32768;

    hipMemsetAsync(Z, 0, (size_t)MROWS * 4, stream);
    hipMemsetAsync(abuf, 0, (size_t)TT * BB * HH * 2, stream);
    hipMemsetAsync(flags, 0, 128 * 16 * 4, stream);
    prep_reduce<<<513, 256, 0, stream>>>(ih, hh, bias, rs, rn, bsum);
    shconv<<<512, 256, 0, stream>>>(hh, rn, SHb);
    esum_kernel<<<12565, 256, 0, stream>>>(emb, rs, bsum, esum);
    esd_k<<<64, 256, 0, stream>>>(tokens, esum, esd);
    wconv<<<dim3(197, 128), 256, 0, stream>>>(outw, Wb);
    tokd_k<<<64, 256, 0, stream>>>(tokens, tokd);
    recurrence<<<NBLK, 512, 0, stream>>>(state, SHb, esd, S, abuf, flags, out_state);
    gemm_ce<<<64 * 197, 512, 0, stream>>>(S, Wb, outb, tokd, Z, lt);
    loss_reduce<<<1, 1024, 0, stream>>>(Z, lt, out_loss);
}